// Round 4
// baseline (103.387 us; speedup 1.0000x reference)
//
#include <hip/hip_runtime.h>
#include <math.h>

#define BATCH 32
#define TH    256
#define TQn   64
#define DIN   256
#define DD    256   // INTERNAL
#define QT    8     // q's per attn block (halves L2 traffic vs QT=4)
#define E2C   2.885390081777927f   // 2*log2(e): exp(2x) == exp2(x*E2C)
#define NL2E  -2.8853900817779268f // -2*log2(e) for unshifted softmax exp2
#define ASTR  12                   // s_alphaT row stride (8 q + 4 pad)

typedef __attribute__((ext_vector_type(8)))  short bf16x8;   // 8 bf16 = 4 VGPRs
typedef __attribute__((ext_vector_type(16))) float floatx16;
typedef __attribute__((ext_vector_type(4)))  float f32x4;
typedef __attribute__((ext_vector_type(2)))  float f32x2;

// exp2(E2C*x) clamped to 2^15: den=1+P*K <= 2^30+1, pair product <= 2^61,
// quad product <= 2^122 — finite through the QUAD-tree rational combine with
// no per-element clamps.
__device__ __forceinline__ float eclamp(float x) {
    return __builtin_amdgcn_exp2f(fminf(x * E2C, 15.f));
}

// ---- packed dual-f32 VOP3P helpers (hipcc never auto-forms v_pk_*_f32) ----
__device__ __forceinline__ f32x2 pk_fma_s(f32x2 a, f32x2 b, f32x2 c) {
    f32x2 d;
    asm("v_pk_fma_f32 %0, %1, %2, %3" : "=v"(d) : "s"(a), "v"(b), "v"(c));
    return d;
}
__device__ __forceinline__ f32x2 pk_fma_v(f32x2 a, f32x2 b, f32x2 c) {
    f32x2 d;
    asm("v_pk_fma_f32 %0, %1, %2, %3" : "=v"(d) : "v"(a), "v"(b), "v"(c));
    return d;
}
__device__ __forceinline__ f32x2 pk_mul_s(f32x2 a, f32x2 b) {
    f32x2 d;
    asm("v_pk_mul_f32 %0, %1, %2" : "=v"(d) : "s"(a), "v"(b));
    return d;
}
__device__ __forceinline__ f32x2 pk_mul_v(f32x2 a, f32x2 b) {
    f32x2 d;
    asm("v_pk_mul_f32 %0, %1, %2" : "=v"(d) : "v"(a), "v"(b));
    return d;
}

// ---- split2 via v_cvt_pk_bf16_f32 (gfx950 HW packed bf16 convert) ----
__device__ __forceinline__ unsigned cvt_pk_bf16(float x0, float x1) {
    unsigned r;   // r = (bf16(x1) << 16) | bf16(x0)
    asm("v_cvt_pk_bf16_f32 %0, %1, %2" : "=v"(r) : "v"(x0), "v"(x1));
    return r;
}
__device__ __forceinline__ void split2(float x0, float x1, unsigned& hi, unsigned& lo) {
    unsigned h = cvt_pk_bf16(x0, x1);
    float f0 = __uint_as_float(h << 16);          // f32 value of bf16(x0)
    float f1 = __uint_as_float(h & 0xFFFF0000u);  // f32 value of bf16(x1)
    hi = h;
    lo = cvt_pk_bf16(x0 - f0, x1 - f1);
}

__device__ __forceinline__ void split8(float4 f0, float4 f1, uint4& hi, uint4& lo) {
    split2(f0.x, f0.y, hi.x, lo.x);
    split2(f0.z, f0.w, hi.y, lo.y);
    split2(f1.x, f1.y, hi.z, lo.z);
    split2(f1.z, f1.w, hi.w, lo.w);
}

// ---------------------------------------------------------------------------
// Kernel 1: projections via bf16-split MFMA (unchanged).
// ---------------------------------------------------------------------------
#define REG4  65                    // uint4 per region (64 + 1 pad)
#define WOFF  (16 * REG4)           // W base in uint4 units
#define TSTR  68                    // transpose LDS stride (17*16B rows)
__global__ __launch_bounds__(256, 4)
void proj_kernel(const float* __restrict__ keys,
                 const float* __restrict__ state,
                 const float* __restrict__ w1,
                 const float* __restrict__ w2,
                 const float* __restrict__ vvec,
                 float* __restrict__ ktp,
                 float* __restrict__ qpo,
                 float* __restrict__ vperm)
{
    __shared__ uint4 lds4[2 * 16 * REG4];   // 32.5 KB (reused for transpose)

    const int bid = blockIdx.x;
    const int tid = threadIdx.x;

    const float* X;
    const float* W;
    int m0, n0;
    bool is_kp;
    if (bid < 512) {
        is_kp = true;
        m0 = (bid >> 2) * 64;
        n0 = (bid & 3) * 64;
        X = keys; W = w1;
    } else {
        is_kp = false;
        int lb = bid - 512;
        m0 = (lb >> 2) * 64;
        n0 = (lb & 3) * 64;
        X = state; W = w2;
    }

    const int w    = tid >> 6;        // wave 0..3
    const int l    = tid & 63;
    const int mt   = w >> 1;          // m half-tile
    const int nt   = w & 1;           // n half-tile
    const int srow = tid >> 3;        // 0..31
    const int kg   = tid & 7;         // 0..7
    const int s_s  = kg >> 1;         // k-step 0..3
    const int lidx = (srow & 31) + 32 * (kg & 1);

    floatx16 acc = {};

    #pragma unroll
    for (int k0 = 0; k0 < DIN; k0 += 64) {
        #pragma unroll
        for (int hrow = 0; hrow < 2; hrow++) {
            int m = srow + hrow * 32;
            const float* px = X + (size_t)(m0 + m) * DIN + k0 + kg * 8;
            uint4 hi, lo;
            split8(*(const float4*)px, *(const float4*)(px + 4), hi, lo);
            int g = m >> 5;
            lds4[((0 * 2 + g) * 4 + s_s) * REG4 + lidx] = hi;
            lds4[((2 + g) * 4 + s_s) * REG4 + lidx] = lo;
            const float* pw = W + (size_t)(n0 + m) * DIN + k0 + kg * 8;
            split8(*(const float4*)pw, *(const float4*)(pw + 4), hi, lo);
            lds4[WOFF + ((0 * 2 + g) * 4 + s_s) * REG4 + lidx] = hi;
            lds4[WOFF + ((2 + g) * 4 + s_s) * REG4 + lidx] = lo;
        }
        __syncthreads();

        #pragma unroll
        for (int s = 0; s < 4; s++) {
            uint4 ahr = lds4[((0 * 2 + mt) * 4 + s) * REG4 + l];
            uint4 alr = lds4[((2 + mt) * 4 + s) * REG4 + l];
            uint4 bhr = lds4[WOFF + ((0 * 2 + nt) * 4 + s) * REG4 + l];
            uint4 blr = lds4[WOFF + ((2 + nt) * 4 + s) * REG4 + l];
            bf16x8 ah = __builtin_bit_cast(bf16x8, ahr);
            bf16x8 al = __builtin_bit_cast(bf16x8, alr);
            bf16x8 bh = __builtin_bit_cast(bf16x8, bhr);
            bf16x8 bl = __builtin_bit_cast(bf16x8, blr);
            acc = __builtin_amdgcn_mfma_f32_32x32x16_bf16(ah, bh, acc, 0, 0, 0);
            acc = __builtin_amdgcn_mfma_f32_32x32x16_bf16(al, bh, acc, 0, 0, 0);
            acc = __builtin_amdgcn_mfma_f32_32x32x16_bf16(ah, bl, acc, 0, 0, 0);
        }
        __syncthreads();
    }

    // C/D map: col=l&31 (n=d), row=(r&3)+8*(r>>2)+4*(l>>5) (m=t/row)
    const int col = l & 31;
    const int hl  = l >> 5;
    if (is_kp) {
        // ---- transpose tile through LDS to d-packed layout ----
        float* sT = (float*)lds4;            // sT[t_local][d_local], stride TSTR
        const int d_local = nt * 32 + col;
        #pragma unroll
        for (int r = 0; r < 16; r++) {
            int t_local = mt * 32 + 4 * hl + 8 * (r >> 2) + (r & 3);
            sT[t_local * TSTR + d_local] = eclamp(acc[r]);
        }
        __syncthreads();
        const int b  = m0 >> 8;
        const int t0 = m0 & 255;
        float4* dst4 = (float4*)ktp;
        #pragma unroll
        for (int p = 0; p < 4; p++) {
            int dp_local = w * 4 + p;                 // 0..15
            float4 v4 = *(float4*)&sT[l * TSTR + dp_local * 4];
            float4 w4;                                 // quad perm (0,2,1,3)
            w4.x = v4.x; w4.y = v4.z; w4.z = v4.y; w4.w = v4.w;
            dst4[(size_t)(b * 64 + (n0 >> 2) + dp_local) * 256 + t0 + l] = w4;
        }
    } else {
        const int d  = n0 + nt * 32 + col;
        const int dl = d & 3;
        const int dsd = (d & ~3) | ((dl & 1) << 1) | (dl >> 1);  // swap slots 1<->2
        #pragma unroll
        for (int r = 0; r < 16; r++) {
            int row = (r & 3) + 8 * (r >> 2) + 4 * hl;
            qpo[(size_t)(m0 + mt * 32 + row) * DD + dsd] = eclamp(acc[r]);
        }
        if (bid == 512 && tid < 256) {
            int jl = tid & 3;
            vperm[tid] = vvec[(tid & ~3) | ((jl & 1) << 1) | (jl >> 1)];
        }
    }
}

// ---------------------------------------------------------------------------
// Kernel 2 (R4): QT=8 per block at 1024 threads, 256 blocks.
// R3's regression diagnosed as occupancy: 256 blocks x 512 thr = 8 waves/CU
// (2/SIMD) — latency exposed. This keeps QT=8's halved L2 traffic (128 MB)
// but restores 16 waves/CU: dgu = tid>>8 in {0..3} handles 64 d's (16
// packed quads) in scores; context uses all 16 waves as (t-quarter dgu x
// i-quad-group iqg), q-pair-packed v_pk_fma accumulate (cq[4][4] f32x2).
// Alphas transposed s_alphaT[t][q] (stride 12): 2x ds_read_b128 per step.
// ---------------------------------------------------------------------------
__global__ __launch_bounds__(1024, 4)
void attn_kernel(const float* __restrict__ keys,
                 const float* __restrict__ vvec,   // permuted copy (ws)
                 const float* __restrict__ ktp,
                 const float* __restrict__ qp,
                 float* __restrict__ out)
{
    __shared__ float s_part[4][QT][TH];    // 32 KB: score partials, then ctx partials
    __shared__ float s_alphaT[TH][ASTR];   // 12 KB, transposed alphas
    __shared__ float s_rsum[QT];

    const int bid  = blockIdx.x;
    const int b    = bid & 31;            // bid%8 == b%8 -> XCD-local batch
    const int q0   = (bid >> 5) * QT;
    const int tid  = threadIdx.x;
    const int t    = tid & 255;
    const int dgu  = __builtin_amdgcn_readfirstlane(tid >> 8);  // quarter, uniform
    const int lane = tid & 63;
    const int wv   = tid >> 6;            // 0..15

    // ---- scores (this quarter's 64 d's = 16 packed quads) ----
    float acc[QT];
    #pragma unroll
    for (int q = 0; q < QT; q++) acc[q] = 0.f;

    const float4* kb4 = (const float4*)ktp + ((size_t)(b * 64 + dgu * 16) * 256 + t);
    const float* pqb  = qp + (size_t)(b * TQn + q0) * DD + dgu * 64;
    const float* vvp  = vvec + dgu * 64;

    const f32x2 one2 = {1.f, 1.f};

    float4 kv0 = kb4[0 * 256], kv1 = kb4[1 * 256],
           kv2 = kb4[2 * 256], kv3 = kb4[3 * 256];

    #pragma unroll
    for (int c = 0; c < 4; c++) {
        float4 n0v, n1v, n2v, n3v;
        if (c < 3) {
            const float4* p = kb4 + (size_t)(c + 1) * 4 * 256;
            n0v = p[0 * 256]; n1v = p[1 * 256];
            n2v = p[2 * 256]; n3v = p[3 * 256];
        }
        #pragma unroll
        for (int u = 0; u < 4; u++) {
            const int dp = c * 4 + u;
            float4 kv = (u == 0) ? kv0 : (u == 1) ? kv1 : (u == 2) ? kv2 : kv3;
            f32x2 KA = {kv.x, kv.y};          // (k0,k2)
            f32x2 KB = {kv.z, kv.w};          // (k1,k3)
            f32x4 V4 = *(const f32x4*)(vvp + dp * 4);   // (v0,v2,v1,v3)
            f32x2 VA = {V4[0], V4[1]};
            f32x2 VB = {V4[2], V4[3]};
            #pragma unroll
            for (int q = 0; q < QT; q++) {
                f32x4 P4 = *(const f32x4*)(pqb + q * DD + dp * 4);  // (p0,p2,p1,p3)
                f32x2 PA = {P4[0], P4[1]};
                f32x2 PB = {P4[2], P4[3]};
                f32x2 A = pk_fma_s(PA, KA, one2);   // (d0,d2)
                f32x2 B = pk_fma_s(PB, KB, one2);   // (d1,d3)
                f32x2 D = pk_mul_v(A, B);           // (d01,d23)
                f32x2 T = pk_mul_s(VA, B);          // (v0d1, v2d3)
                f32x2 N = pk_fma_s(VB, A, T);       // (n01,n23)
                float num = fmaf(N[1], D[0], N[0] * D[1]);
                float den = D[0] * D[1];
                acc[q] = fmaf(num, __builtin_amdgcn_rcpf(den), acc[q]);
            }
        }
        if (c < 3) { kv0 = n0v; kv1 = n1v; kv2 = n2v; kv3 = n3v; }
    }

    #pragma unroll
    for (int q = 0; q < QT; q++) s_part[dgu][q][t] = acc[q];
    __syncthreads();

    // ---- softmax over t=256, no max shift; wave wv (<QT) owns q=wv ----
    if (wv < QT) {
        const int q = wv;
        float p0 = s_part[0][q][lane]       + s_part[1][q][lane]
                 + s_part[2][q][lane]       + s_part[3][q][lane];
        float p1 = s_part[0][q][lane + 64]  + s_part[1][q][lane + 64]
                 + s_part[2][q][lane + 64]  + s_part[3][q][lane + 64];
        float p2 = s_part[0][q][lane + 128] + s_part[1][q][lane + 128]
                 + s_part[2][q][lane + 128] + s_part[3][q][lane + 128];
        float p3 = s_part[0][q][lane + 192] + s_part[1][q][lane + 192]
                 + s_part[2][q][lane + 192] + s_part[3][q][lane + 192];
        float e0 = __builtin_amdgcn_exp2f(p0 * NL2E);
        float e1 = __builtin_amdgcn_exp2f(p1 * NL2E);
        float e2 = __builtin_amdgcn_exp2f(p2 * NL2E);
        float e3 = __builtin_amdgcn_exp2f(p3 * NL2E);
        s_alphaT[lane][q]       = e0;
        s_alphaT[lane + 64][q]  = e1;
        s_alphaT[lane + 128][q] = e2;
        s_alphaT[lane + 192][q] = e3;
        float s = (e0 + e1) + (e2 + e3);
        #pragma unroll
        for (int off = 32; off >= 1; off >>= 1) s += __shfl_xor(s, off);
        if (lane == 0) s_rsum[q] = 1.f / s;
    }
    __syncthreads();

    // ---- context: wave = (t-quarter dgu, i-quad group iqg); lane = (tl, il)
    {
        const int iqg = __builtin_amdgcn_readfirstlane((tid >> 6) & 3);
        const int il  = lane & 15;
        const int tl  = lane >> 4;            // 0..3 (t sub-offset)
        const int iq  = iqg * 16 + il;        // i-quad 0..63

        f32x2 cq[4][4] = {};                  // [q-pair][i] — 32 VGPR
        const float* kp0 = keys + ((size_t)b * TH + dgu * 64 + tl) * DIN + iq * 4;

        #pragma unroll 4
        for (int step = 0; step < 16; step++) {
            f32x4 key4 = *(const f32x4*)(kp0 + (size_t)step * 4 * DIN);
            const int ta = dgu * 64 + step * 4 + tl;
            f32x4 a03 = *(const f32x4*)&s_alphaT[ta][0];   // (a_q0..a_q3)
            f32x4 a47 = *(const f32x4*)&s_alphaT[ta][4];   // (a_q4..a_q7)
            f32x2 ap[4] = {{a03[0], a03[1]}, {a03[2], a03[3]},
                           {a47[0], a47[1]}, {a47[2], a47[3]}};
            #pragma unroll
            for (int i = 0; i < 4; i++) {
                f32x2 kb = {key4[i], key4[i]};             // broadcast dup
                #pragma unroll
                for (int qp2 = 0; qp2 < 4; qp2++)
                    cq[qp2][i] = pk_fma_v(ap[qp2], kb, cq[qp2][i]);
            }
        }

        // reduce across tl: lanes {l, l^16, l^32, l^48} hold same iq
        #pragma unroll
        for (int qp2 = 0; qp2 < 4; qp2++) {
            #pragma unroll
            for (int i = 0; i < 4; i++) {
                #pragma unroll
                for (int h = 0; h < 2; h++) {
                    cq[qp2][i][h] += __shfl_xor(cq[qp2][i][h], 16);
                    cq[qp2][i][h] += __shfl_xor(cq[qp2][i][h], 32);
                }
            }
        }
        if (tl == 0) {
            #pragma unroll
            for (int qp2 = 0; qp2 < 4; qp2++) {
                #pragma unroll
                for (int i = 0; i < 4; i++) {
                    s_part[dgu][2 * qp2 + 0][iq * 4 + i] = cq[qp2][i][0];
                    s_part[dgu][2 * qp2 + 1][iq * 4 + i] = cq[qp2][i][1];
                }
            }
        }
    }
    __syncthreads();

    // ---- final reduce + normalize + store (dwordx4); 512 thr = 8q x 64iq ----
    if (tid < 512) {
        const int q = tid >> 6, iqf = tid & 63;
        f32x4 s = *(const f32x4*)&s_part[0][q][iqf * 4];
        s += *(const f32x4*)&s_part[1][q][iqf * 4];
        s += *(const f32x4*)&s_part[2][q][iqf * 4];
        s += *(const f32x4*)&s_part[3][q][iqf * 4];
        s *= s_rsum[q];
        *(f32x4*)&out[(size_t)(b * TQn + q0 + q) * DIN + iqf * 4] = s;
    }
}

// ---------------------------------------------------------------------------
extern "C" void kernel_launch(void* const* d_in, const int* in_sizes, int n_in,
                              void* d_out, int out_size, void* d_ws, size_t ws_size,
                              hipStream_t stream) {
    (void)in_sizes; (void)n_in; (void)out_size; (void)ws_size;
    const float* keys  = (const float*)d_in[0];  // [32*256][256]
    const float* state = (const float*)d_in[1];  // [32*64][256]
    const float* w1    = (const float*)d_in[2];  // [256][256]
    const float* w2    = (const float*)d_in[3];  // [256][256]
    const float* v     = (const float*)d_in[4];  // [256]
    float* out = (float*)d_out;                  // [2048][256]

    float* ktp = (float*)d_ws;                         // Ktp packed: 8 MB
    float* qp  = ktp + (size_t)BATCH * DD * TH;        // Pq: 2 MB
    float* vp  = qp + (size_t)BATCH * TQn * DD;        // permuted v: 1 KB

    hipLaunchKernelGGL(proj_kernel, dim3(640), dim3(256), 0, stream,
                       keys, state, w1, w2, v, ktp, qp, vp);
    hipLaunchKernelGGL(attn_kernel, dim3(BATCH * (TQn / QT)), dim3(1024), 0, stream,
                       keys, vp, ktp, qp, out);
}

// Round 5
// 99.454 us; speedup vs baseline: 1.0395x; 1.0395x over previous
//
#include <hip/hip_runtime.h>
#include <math.h>

#define BATCH 32
#define TH    256
#define TQn   64
#define DIN   256
#define DD    256   // INTERNAL
#define QT    4     // q's per attn block (QT=8 regressed in R3/R4 — reverted)
#define E2C   2.885390081777927f   // 2*log2(e): exp(2x) == exp2(x*E2C)
#define NL2E  -2.8853900817779268f // -2*log2(e) for unshifted softmax exp2

typedef __attribute__((ext_vector_type(8)))  short bf16x8;   // 8 bf16 = 4 VGPRs
typedef __attribute__((ext_vector_type(16))) float floatx16;
typedef __attribute__((ext_vector_type(4)))  float f32x4;
typedef __attribute__((ext_vector_type(2)))  float f32x2;

// exp2(E2C*x) clamped to 2^15: den=1+P*K <= 2^30+1, pair product <= 2^61,
// quad product <= 2^122 — finite through the QUAD-tree rational combine.
__device__ __forceinline__ float eclamp(float x) {
    return __builtin_amdgcn_exp2f(fminf(x * E2C, 15.f));
}

// ---- packed dual-f32 VOP3P helpers (hipcc never auto-forms v_pk_*_f32) ----
__device__ __forceinline__ f32x2 pk_fma_s(f32x2 a, f32x2 b, f32x2 c) {
    f32x2 d;
    asm("v_pk_fma_f32 %0, %1, %2, %3" : "=v"(d) : "s"(a), "v"(b), "v"(c));
    return d;
}
__device__ __forceinline__ f32x2 pk_mul_s(f32x2 a, f32x2 b) {
    f32x2 d;
    asm("v_pk_mul_f32 %0, %1, %2" : "=v"(d) : "s"(a), "v"(b));
    return d;
}
__device__ __forceinline__ f32x2 pk_mul_v(f32x2 a, f32x2 b) {
    f32x2 d;
    asm("v_pk_mul_f32 %0, %1, %2" : "=v"(d) : "v"(a), "v"(b));
    return d;
}

// ---- split2 via v_cvt_pk_bf16_f32 (gfx950 HW packed bf16 convert) ----
__device__ __forceinline__ unsigned cvt_pk_bf16(float x0, float x1) {
    unsigned r;   // r = (bf16(x1) << 16) | bf16(x0)
    asm("v_cvt_pk_bf16_f32 %0, %1, %2" : "=v"(r) : "v"(x0), "v"(x1));
    return r;
}
__device__ __forceinline__ void split2(float x0, float x1, unsigned& hi, unsigned& lo) {
    unsigned h = cvt_pk_bf16(x0, x1);
    float f0 = __uint_as_float(h << 16);          // f32 value of bf16(x0)
    float f1 = __uint_as_float(h & 0xFFFF0000u);  // f32 value of bf16(x1)
    hi = h;
    lo = cvt_pk_bf16(x0 - f0, x1 - f1);
}

__device__ __forceinline__ void split8(float4 f0, float4 f1, uint4& hi, uint4& lo) {
    split2(f0.x, f0.y, hi.x, lo.x);
    split2(f0.z, f0.w, hi.y, lo.y);
    split2(f1.x, f1.y, hi.z, lo.z);
    split2(f1.z, f1.w, hi.w, lo.w);
}

// ---------------------------------------------------------------------------
// Kernel 1: projections via bf16-split MFMA (3x mfma_f32_32x32x16_bf16).
// R5: XCD-aligned block remap. attn block for batch b runs on XCD b%8
// (bid%8 == b%8 there). Here each XCD x owns batches {x, x+8, x+16, x+24},
// 20 tiles each (16 kp + 4 qp) = 80 blocks = 640/8 — so ktp/qp stores land
// in the same per-XCD L2 that attn reads from (previously round-robin
// across all 8 XCDs -> guaranteed cross-XCD misses).
// ---------------------------------------------------------------------------
#define REG4  65                    // uint4 per region (64 + 1 pad)
#define WOFF  (16 * REG4)           // W base in uint4 units
#define TSTR  68                    // transpose LDS stride (17*16B rows)
__global__ __launch_bounds__(256, 4)
void proj_kernel(const float* __restrict__ keys,
                 const float* __restrict__ state,
                 const float* __restrict__ w1,
                 const float* __restrict__ w2,
                 const float* __restrict__ vvec,
                 float* __restrict__ ktp,
                 float* __restrict__ qpo,
                 float* __restrict__ vperm)
{
    __shared__ uint4 lds4[2 * 16 * REG4];   // 32.5 KB (reused for transpose)

    const int bid = blockIdx.x;
    const int tid = threadIdx.x;

    // ---- XCD-aligned tile mapping: batch % 8 == bid % 8 ----
    const int xcd  = bid & 7;
    const int slot = bid >> 3;            // 0..79
    const int bb   = xcd + 8 * (slot / 20);   // batch 0..31
    const int j    = slot % 20;           // tile within batch

    const float* X;
    const float* W;
    int m0, n0;
    bool is_kp;
    if (j < 16) {
        is_kp = true;
        m0 = bb * 256 + (j >> 2) * 64;
        n0 = (j & 3) * 64;
        X = keys; W = w1;
    } else {
        is_kp = false;
        m0 = bb * 64;
        n0 = (j - 16) * 64;
        X = state; W = w2;
    }

    const int w    = tid >> 6;        // wave 0..3
    const int l    = tid & 63;
    const int mt   = w >> 1;          // m half-tile
    const int nt   = w & 1;           // n half-tile
    const int srow = tid >> 3;        // 0..31
    const int kg   = tid & 7;         // 0..7
    const int s_s  = kg >> 1;         // k-step 0..3
    const int lidx = (srow & 31) + 32 * (kg & 1);

    floatx16 acc = {};

    #pragma unroll
    for (int k0 = 0; k0 < DIN; k0 += 64) {
        #pragma unroll
        for (int hrow = 0; hrow < 2; hrow++) {
            int m = srow + hrow * 32;
            const float* px = X + (size_t)(m0 + m) * DIN + k0 + kg * 8;
            uint4 hi, lo;
            split8(*(const float4*)px, *(const float4*)(px + 4), hi, lo);
            int g = m >> 5;
            lds4[((0 * 2 + g) * 4 + s_s) * REG4 + lidx] = hi;
            lds4[((2 + g) * 4 + s_s) * REG4 + lidx] = lo;
            const float* pw = W + (size_t)(n0 + m) * DIN + k0 + kg * 8;
            split8(*(const float4*)pw, *(const float4*)(pw + 4), hi, lo);
            lds4[WOFF + ((0 * 2 + g) * 4 + s_s) * REG4 + lidx] = hi;
            lds4[WOFF + ((2 + g) * 4 + s_s) * REG4 + lidx] = lo;
        }
        __syncthreads();

        #pragma unroll
        for (int s = 0; s < 4; s++) {
            uint4 ahr = lds4[((0 * 2 + mt) * 4 + s) * REG4 + l];
            uint4 alr = lds4[((2 + mt) * 4 + s) * REG4 + l];
            uint4 bhr = lds4[WOFF + ((0 * 2 + nt) * 4 + s) * REG4 + l];
            uint4 blr = lds4[WOFF + ((2 + nt) * 4 + s) * REG4 + l];
            bf16x8 ah = __builtin_bit_cast(bf16x8, ahr);
            bf16x8 al = __builtin_bit_cast(bf16x8, alr);
            bf16x8 bh = __builtin_bit_cast(bf16x8, bhr);
            bf16x8 bl = __builtin_bit_cast(bf16x8, blr);
            acc = __builtin_amdgcn_mfma_f32_32x32x16_bf16(ah, bh, acc, 0, 0, 0);
            acc = __builtin_amdgcn_mfma_f32_32x32x16_bf16(al, bh, acc, 0, 0, 0);
            acc = __builtin_amdgcn_mfma_f32_32x32x16_bf16(ah, bl, acc, 0, 0, 0);
        }
        __syncthreads();
    }

    // C/D map: col=l&31 (n=d), row=(r&3)+8*(r>>2)+4*(l>>5) (m=t/row)
    const int col = l & 31;
    const int hl  = l >> 5;
    if (is_kp) {
        // ---- transpose tile through LDS to d-packed layout ----
        float* sT = (float*)lds4;            // sT[t_local][d_local], stride TSTR
        const int d_local = nt * 32 + col;
        #pragma unroll
        for (int r = 0; r < 16; r++) {
            int t_local = mt * 32 + 4 * hl + 8 * (r >> 2) + (r & 3);
            sT[t_local * TSTR + d_local] = eclamp(acc[r]);
        }
        __syncthreads();
        const int b  = m0 >> 8;
        const int t0 = m0 & 255;
        float4* dst4 = (float4*)ktp;
        #pragma unroll
        for (int p = 0; p < 4; p++) {
            int dp_local = w * 4 + p;                 // 0..15
            float4 v4 = *(float4*)&sT[l * TSTR + dp_local * 4];
            float4 w4;                                 // quad perm (0,2,1,3)
            w4.x = v4.x; w4.y = v4.z; w4.z = v4.y; w4.w = v4.w;
            dst4[(size_t)(b * 64 + (n0 >> 2) + dp_local) * 256 + t0 + l] = w4;
        }
    } else {
        const int d  = n0 + nt * 32 + col;
        const int dl = d & 3;
        const int dsd = (d & ~3) | ((dl & 1) << 1) | (dl >> 1);  // swap slots 1<->2
        #pragma unroll
        for (int r = 0; r < 16; r++) {
            int row = (r & 3) + 8 * (r >> 2) + 4 * hl;
            qpo[(size_t)(m0 + mt * 32 + row) * DD + dsd] = eclamp(acc[r]);
        }
        if (!is_kp && bb == 0 && n0 == 0 && tid < 256) {
            int jl = tid & 3;
            vperm[tid] = vvec[(tid & ~3) | ((jl & 1) << 1) | (jl >> 1)];
        }
    }
}

// ---------------------------------------------------------------------------
// Kernel 2: fused scores + softmax + context — exact revert to the R2-benched
// kernel (our best: 101.7 us raw / ~12.9 us fill-normalized). QT=4, 1024 thr,
// 512 blocks, __launch_bounds__(1024,8) -> 2 blocks/CU = 32 waves/CU.
// Packed dual-f32 quad-tree rational combine; Pq/vperm via wave-uniform
// s_load; kv 4-deep batched prefetch; softmax without max-shift; context
// f32x4 FMA + shfl_xor reduce + dwordx4 stores.
// ---------------------------------------------------------------------------
__global__ __launch_bounds__(1024, 8)
void attn_kernel(const float* __restrict__ keys,
                 const float* __restrict__ vvec,   // permuted copy (ws)
                 const float* __restrict__ ktp,
                 const float* __restrict__ qp,
                 float* __restrict__ out)
{
    __shared__ float s_part[4][QT][TH];   // 16 KB: score partials, then ctx partials
    __shared__ float s_alpha[QT][TH];     // 4 KB
    __shared__ float s_rsum[QT];

    const int bid  = blockIdx.x;
    const int b    = bid & 31;            // bid%8 == b%8 -> XCD-local batch
    const int q0   = (bid >> 5) * QT;
    const int tid  = threadIdx.x;
    const int t    = tid & 255;
    const int dgu  = __builtin_amdgcn_readfirstlane(tid >> 8);  // quarter, uniform
    const int lane = tid & 63;
    const int wv   = tid >> 6;

    // ---- scores (this quarter's 64 d's = 16 packed quads) ----
    float acc[QT];
    #pragma unroll
    for (int q = 0; q < QT; q++) acc[q] = 0.f;

    const float4* kb4 = (const float4*)ktp + ((size_t)(b * 64 + dgu * 16) * 256 + t);
    const float* pqr0 = qp + (size_t)(b * TQn + q0 + 0) * DD + dgu * 64;
    const float* pqr1 = qp + (size_t)(b * TQn + q0 + 1) * DD + dgu * 64;
    const float* pqr2 = qp + (size_t)(b * TQn + q0 + 2) * DD + dgu * 64;
    const float* pqr3 = qp + (size_t)(b * TQn + q0 + 3) * DD + dgu * 64;
    const float* vvp  = vvec + dgu * 64;

    const f32x2 one2 = {1.f, 1.f};

    float4 kv0 = kb4[0 * 256], kv1 = kb4[1 * 256],
           kv2 = kb4[2 * 256], kv3 = kb4[3 * 256];

    #pragma unroll
    for (int c = 0; c < 4; c++) {
        float4 n0v, n1v, n2v, n3v;
        if (c < 3) {
            const float4* p = kb4 + (size_t)(c + 1) * 4 * 256;
            n0v = p[0 * 256]; n1v = p[1 * 256];
            n2v = p[2 * 256]; n3v = p[3 * 256];
        }
        #pragma unroll
        for (int u = 0; u < 4; u++) {
            const int dp = c * 4 + u;
            float4 kv = (u == 0) ? kv0 : (u == 1) ? kv1 : (u == 2) ? kv2 : kv3;
            f32x2 KA = {kv.x, kv.y};          // (k0,k2)
            f32x2 KB = {kv.z, kv.w};          // (k1,k3)
            f32x4 V4 = *(const f32x4*)(vvp + dp * 4);   // (v0,v2,v1,v3)
            f32x2 VA = {V4[0], V4[1]};
            f32x2 VB = {V4[2], V4[3]};
            const float* pqr[QT] = {pqr0, pqr1, pqr2, pqr3};
            #pragma unroll
            for (int q = 0; q < QT; q++) {
                const float* pr = pqr[q];
                f32x4 P4 = *(const f32x4*)(pr + dp * 4);  // (p0,p2,p1,p3)
                f32x2 PA = {P4[0], P4[1]};
                f32x2 PB = {P4[2], P4[3]};
                f32x2 A = pk_fma_s(PA, KA, one2);   // (d0,d2)
                f32x2 B = pk_fma_s(PB, KB, one2);   // (d1,d3)
                f32x2 D = pk_mul_v(A, B);           // (d01,d23)
                f32x2 T = pk_mul_s(VA, B);          // (v0d1, v2d3)
                f32x2 N = pk_fma_s(VB, A, T);       // (n01,n23)
                float num = fmaf(N[1], D[0], N[0] * D[1]);
                float den = D[0] * D[1];
                acc[q] = fmaf(num, __builtin_amdgcn_rcpf(den), acc[q]);
            }
        }
        if (c < 3) { kv0 = n0v; kv1 = n1v; kv2 = n2v; kv3 = n3v; }
    }

    #pragma unroll
    for (int q = 0; q < QT; q++) s_part[dgu][q][t] = acc[q];
    __syncthreads();

    // ---- softmax over t=256, no max shift; wave wv (<QT) handles q=wv ----
    if (wv < QT) {
        const int q = wv;
        float p0 = s_part[0][q][lane]       + s_part[1][q][lane]
                 + s_part[2][q][lane]       + s_part[3][q][lane];
        float p1 = s_part[0][q][lane + 64]  + s_part[1][q][lane + 64]
                 + s_part[2][q][lane + 64]  + s_part[3][q][lane + 64];
        float p2 = s_part[0][q][lane + 128] + s_part[1][q][lane + 128]
                 + s_part[2][q][lane + 128] + s_part[3][q][lane + 128];
        float p3 = s_part[0][q][lane + 192] + s_part[1][q][lane + 192]
                 + s_part[2][q][lane + 192] + s_part[3][q][lane + 192];
        float e0 = __builtin_amdgcn_exp2f(p0 * NL2E);
        float e1 = __builtin_amdgcn_exp2f(p1 * NL2E);
        float e2 = __builtin_amdgcn_exp2f(p2 * NL2E);
        float e3 = __builtin_amdgcn_exp2f(p3 * NL2E);
        s_alpha[q][lane]       = e0;
        s_alpha[q][lane + 64]  = e1;
        s_alpha[q][lane + 128] = e2;
        s_alpha[q][lane + 192] = e3;
        float s = (e0 + e1) + (e2 + e3);
        #pragma unroll
        for (int off = 32; off >= 1; off >>= 1) s += __shfl_xor(s, off);
        if (lane == 0) s_rsum[q] = 1.f / s;
    }
    __syncthreads();

    // ---- context: wave = (t-quarter dgu, i-quad group iqg); lane = (tl, il)
    {
        const int iqg = __builtin_amdgcn_readfirstlane((tid >> 6) & 3);
        const int il  = lane & 15;
        const int tl  = lane >> 4;            // 0..3 (t sub-offset)
        const int iq  = iqg * 16 + il;        // i-quad 0..63

        f32x4 ctx4[QT] = {};
        const float* kp0 = keys + ((size_t)b * TH + dgu * 64 + tl) * DIN + iq * 4;

        #pragma unroll 4
        for (int step = 0; step < 16; step++) {
            f32x4 key4 = *(const f32x4*)(kp0 + (size_t)step * 4 * DIN);
            const int ta = dgu * 64 + step * 4 + tl;
            #pragma unroll
            for (int q = 0; q < QT; q++)
                ctx4[q] += key4 * s_alpha[q][ta];
        }

        // reduce across tl: lanes {l, l^16, l^32, l^48} hold same iq
        #pragma unroll
        for (int q = 0; q < QT; q++) {
            #pragma unroll
            for (int k = 0; k < 4; k++) {
                ctx4[q][k] += __shfl_xor(ctx4[q][k], 16);
                ctx4[q][k] += __shfl_xor(ctx4[q][k], 32);
            }
        }
        if (tl == 0) {
            #pragma unroll
            for (int q = 0; q < QT; q++)
                *(f32x4*)&s_part[dgu][q][iq * 4] = ctx4[q];
        }
    }
    __syncthreads();

    // ---- final reduce + normalize + store (dwordx4) ----
    if (tid < 256) {
        const int q = tid >> 6, iqf = tid & 63;
        f32x4 s = *(const f32x4*)&s_part[0][q][iqf * 4];
        s += *(const f32x4*)&s_part[1][q][iqf * 4];
        s += *(const f32x4*)&s_part[2][q][iqf * 4];
        s += *(const f32x4*)&s_part[3][q][iqf * 4];
        s *= s_rsum[q];
        *(f32x4*)&out[(size_t)(b * TQn + q0 + q) * DIN + iqf * 4] = s;
    }
}

// ---------------------------------------------------------------------------
extern "C" void kernel_launch(void* const* d_in, const int* in_sizes, int n_in,
                              void* d_out, int out_size, void* d_ws, size_t ws_size,
                              hipStream_t stream) {
    (void)in_sizes; (void)n_in; (void)out_size; (void)ws_size;
    const float* keys  = (const float*)d_in[0];  // [32*256][256]
    const float* state = (const float*)d_in[1];  // [32*64][256]
    const float* w1    = (const float*)d_in[2];  // [256][256]
    const float* w2    = (const float*)d_in[3];  // [256][256]
    const float* v     = (const float*)d_in[4];  // [256]
    float* out = (float*)d_out;                  // [2048][256]

    float* ktp = (float*)d_ws;                         // Ktp packed: 8 MB
    float* qp  = ktp + (size_t)BATCH * DD * TH;        // Pq: 2 MB
    float* vp  = qp + (size_t)BATCH * TQn * DD;        // permuted v: 1 KB

    hipLaunchKernelGGL(proj_kernel, dim3(640), dim3(256), 0, stream,
                       keys, state, w1, w2, v, ktp, qp, vp);
    hipLaunchKernelGGL(attn_kernel, dim3(BATCH * (TQn / QT)), dim3(1024), 0, stream,
                       keys, vp, ktp, qp, out);
}